// Round 7
// baseline (42.847 us; speedup 1.0000x reference)
//
#include <hip/hip_runtime.h>
#include <cstddef>

// Problem constants (match reference)
constexpr int H_ = 320;
constexpr int W_ = 320;
constexpr int HW_ = H_ * W_;            // 102400
constexpr int NK = 440;                 // offsets excluding center
constexpr int TS = 32;                  // spatial tile edge
constexpr int TPR = W_ / TS;            // 10 tiles per row
constexpr int NTILES = TPR * TPR;       // 100
constexpr int NWORK = NTILES * NK;      // 44000 plane-tile work items
constexpr int NB = 2048;                // exactly 8 blocks/CU
constexpr int NPART = NB + NTILES;      // 2148 partials
constexpr int HALO = 10;
constexpr int LW = TS + 2 * HALO;       // 52
constexpr int LSTRIDE = LW + 1;         // 53 (odd -> worst LDS conflict 2-way = free)

typedef float f32x4 __attribute__((ext_vector_type(4)));

__device__ __forceinline__ int clampi(int v, int lo, int hi) {
    return v < lo ? lo : (v > hi ? hi : v);
}

// full-block reduce; rbuf is 4 floats of shared mem. Leading barrier makes
// repeated calls safe. Result valid on all threads.
__device__ __forceinline__ float block_reduce(float v, float* rbuf, int tid) {
    __syncthreads();
    for (int off = 32; off > 0; off >>= 1)
        v += __shfl_down(v, off, 64);
    if ((tid & 63) == 0) rbuf[tid >> 6] = v;
    __syncthreads();
    return rbuf[0] + rbuf[1] + rbuf[2] + rbuf[3];
}

__global__ __launch_bounds__(256) void bsl_main_kernel(
    const float* __restrict__ img,   // [H,W]
    const float* __restrict__ tgt,   // [H,W]
    const float* __restrict__ w,     // [440,H,W]
    float* __restrict__ partials)    // [NPART]
{
    __shared__ float lds[LW * LSTRIDE];   // 52*53*4 = 11,236 B -> 8 blocks/CU
    __shared__ float rbuf[4];
    const int tid = threadIdx.x;
    const int b = blockIdx.x;

    // contiguous work-item range [r0, r1), tile-major: item = tile*440 + k
    const int r0 = (int)(((long long)b * NWORK) >> 11);
    const int r1 = (int)(((long long)(b + 1) * NWORK) >> 11);

    const int row = tid >> 3;            // 0..31
    const int c4  = (tid & 7) * 4;       // 0,4,...,28

    float sacc = 0.f, sacc2 = 0.f;

    for (int item = r0; item < r1; ) {
        const int t  = item / NK;
        const int ks = item - t * NK;
        const int span = r1 - item;
        const int ke = (NK - ks < span) ? NK : ks + span;   // min(NK, ks+span)
        const int y0 = (t / TPR) * TS, x0 = (t % TPR) * TS;

        // ---- stage img tile + halo into LDS (replicate padding via clamp) ----
        if (item != r0) __syncthreads();     // protect LDS before restage
        for (int e = tid; e < LW * LW; e += 256) {
            const int ly = e / LW, lx = e - ly * LW;
            const int gy = clampi(y0 - HALO + ly, 0, H_ - 1);
            const int gx = clampi(x0 - HALO + lx, 0, W_ - 1);
            lds[ly * LSTRIDE + lx] = img[gy * W_ + gx];
        }
        __syncthreads();

        const int cbase = (HALO + row) * LSTRIDE + HALO + c4;
        const float c0 = lds[cbase + 0];
        const float c1 = lds[cbase + 1];
        const float c2 = lds[cbase + 2];
        const float c3 = lds[cbase + 3];

        // ---- 2-deep software-pipelined stream over planes [ks, ke) ----
        const float* wp = w + (size_t)ks * HW_ + (y0 + row) * W_ + x0 + c4;
        f32x4 wv0 = __builtin_nontemporal_load((const f32x4*)wp);
        f32x4 wv1 = (ks + 1 < ke)
            ? __builtin_nontemporal_load((const f32x4*)(wp + HW_)) : wv0;

        for (int kk = ks; kk < ke; ++kk) {
            const f32x4 wnext = (kk + 2 < ke)
                ? __builtin_nontemporal_load((const f32x4*)(wp + 2 * HW_)) : wv1;

            const int idx = (kk < 220) ? kk : kk + 1;   // re-insert center gap
            const int q   = idx / 21;
            const int nb  = cbase + (q - 10) * LSTRIDE + (idx - q * 21 - 10);

            const float d0 = c0 - lds[nb + 0];
            const float d1 = c1 - lds[nb + 1];
            const float d2 = c2 - lds[nb + 2];
            const float d3 = c3 - lds[nb + 3];
            sacc  += wv0.x * d0 * d0 + wv0.y * d1 * d1;   // split chains
            sacc2 += wv0.z * d2 * d2 + wv0.w * d3 * d3;

            wv0 = wv1; wv1 = wnext; wp += HW_;
        }

        // ---- data term: the unique block owning this tile's k=0 item ----
        if (ks == 0) {
            const float4 t4 = *reinterpret_cast<const float4*>(
                tgt + (y0 + row) * W_ + x0 + c4);
            const float d0 = c0 - t4.x, d1 = c1 - t4.y;
            const float d2 = c2 - t4.z, d3 = c3 - t4.w;
            const float dsum = block_reduce(d0*d0 + d1*d1 + d2*d2 + d3*d3,
                                            rbuf, tid);
            if (tid == 0) partials[NB + t] = dsum;
        }

        item += ke - ks;
    }

    const float ssum = block_reduce(sacc + sacc2, rbuf, tid);
    if (tid == 0) partials[b] = ssum;
}

__global__ __launch_bounds__(256) void bsl_final_kernel(
    const float* __restrict__ partials, float* __restrict__ out)
{
    const int tid = threadIdx.x;
    double s = 0.0, d = 0.0;

    // smooth partials: 2048 floats = 2 rounds of 256 float4
    for (int base = 0; base < NB; base += 1024) {
        const float4 v = *reinterpret_cast<const float4*>(partials + base + tid * 4);
        s += (double)v.x + (double)v.y + (double)v.z + (double)v.w;
    }
    // data partials: 100 floats = 25 float4
    if (tid < NTILES / 4) {
        const float4 v = *reinterpret_cast<const float4*>(partials + NB + tid * 4);
        d += (double)v.x + (double)v.y + (double)v.z + (double)v.w;
    }

    __shared__ double sm[256];
    __shared__ double sd[256];
    sm[tid] = s; sd[tid] = d;
    __syncthreads();
    for (int st = 128; st > 0; st >>= 1) {
        if (tid < st) { sm[tid] += sm[tid + st]; sd[tid] += sd[tid + st]; }
        __syncthreads();
    }
    if (tid == 0) {
        // H*W*LAM*mean(w d^2) = LAM * S / 440 ; data = D / (H*W)
        out[0] = (float)(128.0 * sm[0] / 440.0 + sd[0] / (double)HW_);
    }
}

extern "C" void kernel_launch(void* const* d_in, const int* in_sizes, int n_in,
                              void* d_out, int out_size, void* d_ws, size_t ws_size,
                              hipStream_t stream) {
    const float* img = (const float*)d_in[0];   // output [320,320]
    const float* tgt = (const float*)d_in[1];   // target [320,320]
    const float* wij = (const float*)d_in[2];   // w_ij [440,320,320]
    float* out = (float*)d_out;
    float* partials = (float*)d_ws;             // NPART floats = 8.6 KB

    bsl_main_kernel<<<NB, 256, 0, stream>>>(img, tgt, wij, partials);
    bsl_final_kernel<<<1, 256, 0, stream>>>(partials, out);
}

// Round 8
// 36.453 us; speedup vs baseline: 1.1754x; 1.1754x over previous
//
#include <hip/hip_runtime.h>
#include <cstddef>

// Problem constants (match reference)
constexpr int H_ = 320;
constexpr int W_ = 320;
constexpr int HW_ = H_ * W_;            // 102400
constexpr int NK = 440;                 // offsets excluding center
constexpr int TS = 32;                  // spatial tile edge
constexpr int TPR = W_ / TS;            // 10 tiles per row
constexpr int NTILES = TPR * TPR;       // 100
constexpr int KC = 22;                  // k-offsets per chunk
constexpr int NKC = NK / KC;            // 20 chunks
constexpr int SMOOTH_BLOCKS = NTILES * NKC;   // 2000 (7.81 blocks/CU, small tail)
constexpr int NPART = SMOOTH_BLOCKS + NTILES; // 2100 partials
constexpr int HALO = 10;
constexpr int LW = TS + 2 * HALO;       // 52
constexpr int LSTRIDE = LW + 1;         // 53 (odd -> worst LDS conflict 2-way = free)

typedef float f32x4 __attribute__((ext_vector_type(4)));

__device__ __forceinline__ int clampi(int v, int lo, int hi) {
    return v < lo ? lo : (v > hi ? hi : v);
}

// full-block reduce; rbuf is 4 floats of shared mem. Safe to call twice
// (leading barrier protects rbuf reuse). Result valid on all threads.
__device__ __forceinline__ float block_reduce(float v, float* rbuf, int tid) {
    __syncthreads();
    for (int off = 32; off > 0; off >>= 1)
        v += __shfl_down(v, off, 64);
    if ((tid & 63) == 0) rbuf[tid >> 6] = v;
    __syncthreads();
    return rbuf[0] + rbuf[1] + rbuf[2] + rbuf[3];
}

// __launch_bounds__(256, 8): 8 waves/SIMD -> forces VGPR <= 64 so the full
// 32-wave/CU occupancy is achievable (VGPR cliff at 64, m69).
__global__ __launch_bounds__(256, 8) void bsl_main_kernel(
    const float* __restrict__ img,   // [H,W]
    const float* __restrict__ tgt,   // [H,W]
    const float* __restrict__ w,     // [440,H,W]
    float* __restrict__ partials)    // [NPART]
{
    __shared__ float lds[LW * LSTRIDE];   // 52*53*4 = 11,236 B
    __shared__ float rbuf[4];
    const int tid = threadIdx.x;

    const int tileId = blockIdx.x / NKC;
    const int kc     = blockIdx.x % NKC;
    const int ty = tileId / TPR, tx = tileId % TPR;
    const int y0 = ty * TS, x0 = tx * TS;

    // ---- stage img tile + halo into LDS (replicate padding via clamp) ----
    for (int e = tid; e < LW * LW; e += 256) {
        const int ly = e / LW, lx = e - ly * LW;
        const int gy = clampi(y0 - HALO + ly, 0, H_ - 1);
        const int gx = clampi(x0 - HALO + lx, 0, W_ - 1);
        lds[ly * LSTRIDE + lx] = img[gy * W_ + gx];
    }
    __syncthreads();

    // thread -> 4 consecutive pixels of the 32x32 tile
    const int row = tid >> 3;            // 0..31
    const int c4  = (tid & 7) * 4;       // 0,4,...,28
    const int cbase = (HALO + row) * LSTRIDE + HALO + c4;
    const float c0 = lds[cbase + 0];
    const float c1 = lds[cbase + 1];
    const float c2 = lds[cbase + 2];
    const float c3 = lds[cbase + 3];

    // ---- stream KC w-plane tiles (read-once -> nontemporal) ----
    float sacc = 0.f;
    const float* wp = w + (size_t)(kc * KC) * HW_ + (y0 + row) * W_ + x0 + c4;
#pragma unroll 4
    for (int kk = 0; kk < KC; ++kk) {
        const int bk  = kc * KC + kk;                 // w-plane index (center skipped)
        const int idx = (bk < 220) ? bk : bk + 1;     // re-insert center gap
        const int q   = idx / 21;
        const int di  = q - 10;
        const int dj  = idx - q * 21 - 10;

        const f32x4 w4 = __builtin_nontemporal_load((const f32x4*)wp);
        wp += HW_;

        const int nb = cbase + di * LSTRIDE + dj;     // wave-uniform offset add
        const float n0 = lds[nb + 0];
        const float n1 = lds[nb + 1];
        const float n2 = lds[nb + 2];
        const float n3 = lds[nb + 3];
        const float d0 = c0 - n0, d1 = c1 - n1, d2 = c2 - n2, d3 = c3 - n3;
        sacc += w4.x * d0 * d0;
        sacc += w4.y * d1 * d1;
        sacc += w4.z * d2 * d2;
        sacc += w4.w * d3 * d3;
    }

    const float ssum = block_reduce(sacc, rbuf, tid);
    if (tid == 0) partials[blockIdx.x] = ssum;

    // ---- data term: once per tile (kc==0 blocks) ----
    if (kc == 0) {
        const float4 t4 = *reinterpret_cast<const float4*>(
            tgt + (y0 + row) * W_ + x0 + c4);
        const float d0 = c0 - t4.x, d1 = c1 - t4.y;
        const float d2 = c2 - t4.z, d3 = c3 - t4.w;
        const float dsum = block_reduce(d0*d0 + d1*d1 + d2*d2 + d3*d3, rbuf, tid);
        if (tid == 0) partials[SMOOTH_BLOCKS + tileId] = dsum;
    }
}

__global__ __launch_bounds__(256) void bsl_final_kernel(
    const float* __restrict__ partials, float* __restrict__ out)
{
    const int tid = threadIdx.x;
    double s = 0.0, d = 0.0;

    // smooth partials: 2000 floats; rounds of 256 float4 with bound guard
    for (int base = 0; base < SMOOTH_BLOCKS; base += 1024) {
        const int i = base + tid * 4;
        if (i + 4 <= SMOOTH_BLOCKS) {
            const float4 v = *reinterpret_cast<const float4*>(partials + i);
            s += (double)v.x + (double)v.y + (double)v.z + (double)v.w;
        }
    }
    // data partials: 100 floats
    if (tid < NTILES / 4) {
        const float4 v = *reinterpret_cast<const float4*>(
            partials + SMOOTH_BLOCKS + tid * 4);
        d += (double)v.x + (double)v.y + (double)v.z + (double)v.w;
    }

    __shared__ double sm[256];
    __shared__ double sd[256];
    sm[tid] = s; sd[tid] = d;
    __syncthreads();
    for (int st = 128; st > 0; st >>= 1) {
        if (tid < st) { sm[tid] += sm[tid + st]; sd[tid] += sd[tid + st]; }
        __syncthreads();
    }
    if (tid == 0) {
        // H*W*LAM*mean(w d^2) = LAM * S / 440 ; data = D / (H*W)
        out[0] = (float)(128.0 * sm[0] / 440.0 + sd[0] / (double)HW_);
    }
}

extern "C" void kernel_launch(void* const* d_in, const int* in_sizes, int n_in,
                              void* d_out, int out_size, void* d_ws, size_t ws_size,
                              hipStream_t stream) {
    const float* img = (const float*)d_in[0];   // output [320,320]
    const float* tgt = (const float*)d_in[1];   // target [320,320]
    const float* wij = (const float*)d_in[2];   // w_ij [440,320,320]
    float* out = (float*)d_out;
    float* partials = (float*)d_ws;             // NPART floats = 8.4 KB

    bsl_main_kernel<<<SMOOTH_BLOCKS, 256, 0, stream>>>(img, tgt, wij, partials);
    bsl_final_kernel<<<1, 256, 0, stream>>>(partials, out);
}

// Round 9
// 36.003 us; speedup vs baseline: 1.1901x; 1.0125x over previous
//
#include <hip/hip_runtime.h>
#include <cstddef>

// Problem constants (match reference)
constexpr int H_ = 320;
constexpr int W_ = 320;
constexpr int HW_ = H_ * W_;            // 102400
constexpr int NK = 440;                 // offsets excluding center
constexpr int TY = 16;                  // tile rows
constexpr int TX = 64;                  // tile cols (wave-load = 4 x 256B segments)
constexpr int NTX = W_ / TX;            // 5
constexpr int NTY = H_ / TY;            // 20
constexpr int NTILES = NTX * NTY;       // 100
constexpr int KC = 22;                  // k-offsets per chunk
constexpr int NKC = NK / KC;            // 20 chunks
constexpr int SMOOTH_BLOCKS = NTILES * NKC;   // 2000
constexpr int NPART = SMOOTH_BLOCKS + NTILES; // 2100 partials
constexpr int HALO = 10;
constexpr int LROWS = TY + 2 * HALO;    // 36
constexpr int LCOLS = TX + 2 * HALO;    // 84
constexpr int LSTRIDE = LCOLS + 1;      // 85 (odd -> worst LDS aliasing 2-4 way)

typedef float f32x4 __attribute__((ext_vector_type(4)));

__device__ __forceinline__ int clampi(int v, int lo, int hi) {
    return v < lo ? lo : (v > hi ? hi : v);
}

// full-block reduce; rbuf is 4 floats of shared mem. Safe to call twice
// (leading barrier protects rbuf reuse). Result valid on all threads.
__device__ __forceinline__ float block_reduce(float v, float* rbuf, int tid) {
    __syncthreads();
    for (int off = 32; off > 0; off >>= 1)
        v += __shfl_down(v, off, 64);
    if ((tid & 63) == 0) rbuf[tid >> 6] = v;
    __syncthreads();
    return rbuf[0] + rbuf[1] + rbuf[2] + rbuf[3];
}

__global__ __launch_bounds__(256, 8) void bsl_main_kernel(
    const float* __restrict__ img,   // [H,W]
    const float* __restrict__ tgt,   // [H,W]
    const float* __restrict__ w,     // [440,H,W]
    float* __restrict__ partials)    // [NPART]
{
    __shared__ float lds[LROWS * LSTRIDE];   // 36*85*4 = 12,240 B -> 8 blocks/CU
    __shared__ float rbuf[4];
    const int tid = threadIdx.x;

    const int tileId = blockIdx.x / NKC;
    const int kc     = blockIdx.x % NKC;
    const int ty = tileId / NTX, tx = tileId % NTX;
    const int y0 = ty * TY, x0 = tx * TX;

    // ---- stage img tile + halo into LDS (replicate padding via clamp) ----
    for (int e = tid; e < LROWS * LCOLS; e += 256) {
        const int ly = e / LCOLS, lx = e - ly * LCOLS;
        const int gy = clampi(y0 - HALO + ly, 0, H_ - 1);
        const int gx = clampi(x0 - HALO + lx, 0, W_ - 1);
        lds[ly * LSTRIDE + lx] = img[gy * W_ + gx];
    }
    __syncthreads();

    // thread -> 4 consecutive pixels of the 16x64 tile
    const int row = tid >> 4;            // 0..15 (16 threads per 64-px row)
    const int c4  = (tid & 15) * 4;      // 0,4,...,60
    const int cbase = (HALO + row) * LSTRIDE + HALO + c4;
    const float c0 = lds[cbase + 0];
    const float c1 = lds[cbase + 1];
    const float c2 = lds[cbase + 2];
    const float c3 = lds[cbase + 3];

    // ---- stream KC w-plane tiles (read-once -> nontemporal) ----
    float sacc = 0.f;
    const float* wp = w + (size_t)(kc * KC) * HW_ + (y0 + row) * W_ + x0 + c4;
#pragma unroll 4
    for (int kk = 0; kk < KC; ++kk) {
        const int bk  = kc * KC + kk;                 // w-plane index (center skipped)
        const int idx = (bk < 220) ? bk : bk + 1;     // re-insert center gap
        const int q   = idx / 21;
        const int di  = q - 10;
        const int dj  = idx - q * 21 - 10;

        const f32x4 w4 = __builtin_nontemporal_load((const f32x4*)wp);
        wp += HW_;

        const int nb = cbase + di * LSTRIDE + dj;     // wave-uniform offset add
        const float n0 = lds[nb + 0];
        const float n1 = lds[nb + 1];
        const float n2 = lds[nb + 2];
        const float n3 = lds[nb + 3];
        const float d0 = c0 - n0, d1 = c1 - n1, d2 = c2 - n2, d3 = c3 - n3;
        sacc += w4.x * d0 * d0;
        sacc += w4.y * d1 * d1;
        sacc += w4.z * d2 * d2;
        sacc += w4.w * d3 * d3;
    }

    const float ssum = block_reduce(sacc, rbuf, tid);
    if (tid == 0) partials[blockIdx.x] = ssum;

    // ---- data term: once per tile (kc==0 blocks) ----
    if (kc == 0) {
        const float4 t4 = *reinterpret_cast<const float4*>(
            tgt + (y0 + row) * W_ + x0 + c4);
        const float d0 = c0 - t4.x, d1 = c1 - t4.y;
        const float d2 = c2 - t4.z, d3 = c3 - t4.w;
        const float dsum = block_reduce(d0*d0 + d1*d1 + d2*d2 + d3*d3, rbuf, tid);
        if (tid == 0) partials[SMOOTH_BLOCKS + tileId] = dsum;
    }
}

__global__ __launch_bounds__(256) void bsl_final_kernel(
    const float* __restrict__ partials, float* __restrict__ out)
{
    const int tid = threadIdx.x;
    double s = 0.0, d = 0.0;

    // smooth partials: 2000 floats; rounds of 256 float4 with bound guard
    for (int base = 0; base < SMOOTH_BLOCKS; base += 1024) {
        const int i = base + tid * 4;
        if (i + 4 <= SMOOTH_BLOCKS) {
            const float4 v = *reinterpret_cast<const float4*>(partials + i);
            s += (double)v.x + (double)v.y + (double)v.z + (double)v.w;
        }
    }
    // data partials: 100 floats
    if (tid < NTILES / 4) {
        const float4 v = *reinterpret_cast<const float4*>(
            partials + SMOOTH_BLOCKS + tid * 4);
        d += (double)v.x + (double)v.y + (double)v.z + (double)v.w;
    }

    __shared__ double sm[256];
    __shared__ double sd[256];
    sm[tid] = s; sd[tid] = d;
    __syncthreads();
    for (int st = 128; st > 0; st >>= 1) {
        if (tid < st) { sm[tid] += sm[tid + st]; sd[tid] += sd[tid + st]; }
        __syncthreads();
    }
    if (tid == 0) {
        // H*W*LAM*mean(w d^2) = LAM * S / 440 ; data = D / (H*W)
        out[0] = (float)(128.0 * sm[0] / 440.0 + sd[0] / (double)HW_);
    }
}

extern "C" void kernel_launch(void* const* d_in, const int* in_sizes, int n_in,
                              void* d_out, int out_size, void* d_ws, size_t ws_size,
                              hipStream_t stream) {
    const float* img = (const float*)d_in[0];   // output [320,320]
    const float* tgt = (const float*)d_in[1];   // target [320,320]
    const float* wij = (const float*)d_in[2];   // w_ij [440,320,320]
    float* out = (float*)d_out;
    float* partials = (float*)d_ws;             // NPART floats = 8.4 KB

    bsl_main_kernel<<<SMOOTH_BLOCKS, 256, 0, stream>>>(img, tgt, wij, partials);
    bsl_final_kernel<<<1, 256, 0, stream>>>(partials, out);
}

// Round 11
// 35.980 us; speedup vs baseline: 1.1909x; 1.0006x over previous
//
#include <hip/hip_runtime.h>
#include <cstddef>

// Problem constants (match reference)
constexpr int H_ = 320;
constexpr int W_ = 320;
constexpr int HW_ = H_ * W_;            // 102400
constexpr int NK = 440;                 // offsets excluding center
constexpr int TY = 16;                  // tile rows
constexpr int TX = 64;                  // tile cols (wave-load = 4 x 256B segments)
constexpr int NTX = W_ / TX;            // 5
constexpr int NTY = H_ / TY;            // 20
constexpr int NTILES = NTX * NTY;       // 100
constexpr int KC = 22;                  // k-offsets per chunk
constexpr int NKC = NK / KC;            // 20 chunks
constexpr int SMOOTH_BLOCKS = NTILES * NKC;   // 2000
constexpr int NPART = SMOOTH_BLOCKS + NTILES; // 2100 partials
constexpr int HALO = 10;
constexpr int LROWS = TY + 2 * HALO;    // 36
constexpr int LCOLS = TX + 2 * HALO;    // 84
constexpr int LSTRIDE = LCOLS + 1;      // 85 (odd -> worst LDS aliasing 2-4 way)

typedef float f32x4 __attribute__((ext_vector_type(4)));

__device__ __forceinline__ int clampi(int v, int lo, int hi) {
    return v < lo ? lo : (v > hi ? hi : v);
}

// full-block reduce; rbuf is 4 floats of shared mem. Safe to call twice
// (leading barrier protects rbuf reuse). Result valid on all threads.
__device__ __forceinline__ float block_reduce(float v, float* rbuf, int tid) {
    __syncthreads();
    for (int off = 32; off > 0; off >>= 1)
        v += __shfl_down(v, off, 64);
    if ((tid & 63) == 0) rbuf[tid >> 6] = v;
    __syncthreads();
    return rbuf[0] + rbuf[1] + rbuf[2] + rbuf[3];
}

__global__ __launch_bounds__(256, 8) void bsl_main_kernel(
    const float* __restrict__ img,   // [H,W]
    const float* __restrict__ tgt,   // [H,W]
    const float* __restrict__ w,     // [440,H,W]
    float* __restrict__ partials)    // [NPART]
{
    __shared__ float lds[LROWS * LSTRIDE];   // 36*85*4 = 12,240 B -> 8 blocks/CU
    __shared__ float rbuf[4];
    const int tid = threadIdx.x;

    const int tileId = blockIdx.x / NKC;
    const int kc     = blockIdx.x % NKC;
    const int ty = tileId / NTX, tx = tileId % NTX;
    const int y0 = ty * TY, x0 = tx * TX;

    // ---- stage img tile + halo into LDS (replicate padding via clamp) ----
    for (int e = tid; e < LROWS * LCOLS; e += 256) {
        const int ly = e / LCOLS, lx = e - ly * LCOLS;
        const int gy = clampi(y0 - HALO + ly, 0, H_ - 1);
        const int gx = clampi(x0 - HALO + lx, 0, W_ - 1);
        lds[ly * LSTRIDE + lx] = img[gy * W_ + gx];
    }
    __syncthreads();

    // thread -> 4 consecutive pixels of the 16x64 tile
    const int row = tid >> 4;            // 0..15 (16 threads per 64-px row)
    const int c4  = (tid & 15) * 4;      // 0,4,...,60
    const int cbase = (HALO + row) * LSTRIDE + HALO + c4;
    const float c0 = lds[cbase + 0];
    const float c1 = lds[cbase + 1];
    const float c2 = lds[cbase + 2];
    const float c3 = lds[cbase + 3];

    // ---- stream KC w-plane tiles (read-once -> nontemporal) ----
    float sacc = 0.f;
    const float* wp = w + (size_t)(kc * KC) * HW_ + (y0 + row) * W_ + x0 + c4;
#pragma unroll 4
    for (int kk = 0; kk < KC; ++kk) {
        const int bk  = kc * KC + kk;                 // w-plane index (center skipped)
        const int idx = (bk < 220) ? bk : bk + 1;     // re-insert center gap
        const int q   = idx / 21;
        const int di  = q - 10;
        const int dj  = idx - q * 21 - 10;

        const f32x4 w4 = __builtin_nontemporal_load((const f32x4*)wp);
        wp += HW_;

        const int nb = cbase + di * LSTRIDE + dj;     // wave-uniform offset add
        const float n0 = lds[nb + 0];
        const float n1 = lds[nb + 1];
        const float n2 = lds[nb + 2];
        const float n3 = lds[nb + 3];
        const float d0 = c0 - n0, d1 = c1 - n1, d2 = c2 - n2, d3 = c3 - n3;
        sacc += w4.x * d0 * d0;
        sacc += w4.y * d1 * d1;
        sacc += w4.z * d2 * d2;
        sacc += w4.w * d3 * d3;
    }

    const float ssum = block_reduce(sacc, rbuf, tid);
    if (tid == 0) partials[blockIdx.x] = ssum;

    // ---- data term: once per tile (kc==0 blocks) ----
    if (kc == 0) {
        const float4 t4 = *reinterpret_cast<const float4*>(
            tgt + (y0 + row) * W_ + x0 + c4);
        const float d0 = c0 - t4.x, d1 = c1 - t4.y;
        const float d2 = c2 - t4.z, d3 = c3 - t4.w;
        const float dsum = block_reduce(d0*d0 + d1*d1 + d2*d2 + d3*d3, rbuf, tid);
        if (tid == 0) partials[SMOOTH_BLOCKS + tileId] = dsum;
    }
}

__global__ __launch_bounds__(256) void bsl_final_kernel(
    const float* __restrict__ partials, float* __restrict__ out)
{
    const int tid = threadIdx.x;
    double s = 0.0, d = 0.0;

    // smooth partials: 2000 floats; rounds of 256 float4 with bound guard
    for (int base = 0; base < SMOOTH_BLOCKS; base += 1024) {
        const int i = base + tid * 4;
        if (i + 4 <= SMOOTH_BLOCKS) {
            const float4 v = *reinterpret_cast<const float4*>(partials + i);
            s += (double)v.x + (double)v.y + (double)v.z + (double)v.w;
        }
    }
    // data partials: 100 floats
    if (tid < NTILES / 4) {
        const float4 v = *reinterpret_cast<const float4*>(
            partials + SMOOTH_BLOCKS + tid * 4);
        d += (double)v.x + (double)v.y + (double)v.z + (double)v.w;
    }

    __shared__ double sm[256];
    __shared__ double sd[256];
    sm[tid] = s; sd[tid] = d;
    __syncthreads();
    for (int st = 128; st > 0; st >>= 1) {
        if (tid < st) { sm[tid] += sm[tid + st]; sd[tid] += sd[tid + st]; }
        __syncthreads();
    }
    if (tid == 0) {
        // H*W*LAM*mean(w d^2) = LAM * S / 440 ; data = D / (H*W)
        out[0] = (float)(128.0 * sm[0] / 440.0 + sd[0] / (double)HW_);
    }
}

extern "C" void kernel_launch(void* const* d_in, const int* in_sizes, int n_in,
                              void* d_out, int out_size, void* d_ws, size_t ws_size,
                              hipStream_t stream) {
    const float* img = (const float*)d_in[0];   // output [320,320]
    const float* tgt = (const float*)d_in[1];   // target [320,320]
    const float* wij = (const float*)d_in[2];   // w_ij [440,320,320]
    float* out = (float*)d_out;
    float* partials = (float*)d_ws;             // NPART floats = 8.4 KB

    bsl_main_kernel<<<SMOOTH_BLOCKS, 256, 0, stream>>>(img, tgt, wij, partials);
    bsl_final_kernel<<<1, 256, 0, stream>>>(partials, out);
}